// Round 10
// baseline (232.429 us; speedup 1.0000x reference)
//
#include <hip/hip_runtime.h>
#include <math.h>

#define N_NODES 50000
#define N_EDGES 800000
#define NB1 196  // ceil(50000/256)

typedef __attribute__((ext_vector_type(8))) short bf16x8;
typedef __attribute__((ext_vector_type(4))) float f32x4;

// ---- bf16 helpers (manual RNE) ----
__device__ __forceinline__ unsigned short f2bf(float f) {
    unsigned u = __float_as_uint(f);
    unsigned r = (u + 0x7FFFu + ((u >> 16) & 1u)) >> 16;
    return (unsigned short)r;
}
__device__ __forceinline__ float bf2f(unsigned short u) {
    return __uint_as_float(((unsigned)u) << 16);
}
__device__ __forceinline__ unsigned pack2bf(float a, float b) {
    return (unsigned)f2bf(a) | ((unsigned)f2bf(b) << 16);
}

// Build MFMA B-fragments: We^T (4 frags) + wca-column frags (2) ; zero degi.
// Frag f element (f*512 + lane*8 + j):
//   f<4: B[k=32s+8*(lane>>4)+j][col=16n+(lane&15)] with B[k][j']=We[j'][k], s=f>>1, n=f&1
//   f=4,5: col0 = wca[k] = sum_jj Wa[64+jj]*We[jj][k], other cols 0; s=f-4
__global__ __launch_bounds__(256) void kw_kernel(const float* __restrict__ We,
                                                 const float* __restrict__ Wa,
                                                 short* __restrict__ Bpack,
                                                 int* __restrict__ degi) {
    int t = blockIdx.x * 256 + threadIdx.x;
    if (t < N_NODES) degi[t] = 0;
    if (t < 2048) {
        int s = t >> 10, n = (t >> 9) & 1, lane = (t >> 3) & 63, j = t & 7;
        float v = We[(16 * n + (lane & 15)) * 64 + 32 * s + 8 * (lane >> 4) + j];
        Bpack[t] = (short)f2bf(v);
    } else if (t < 3072) {
        int u = t - 2048;
        int s = u >> 9, lane = (u >> 3) & 63, j = u & 7;
        int k = 32 * s + 8 * (lane >> 4) + j;
        float v = 0.f;
        if ((lane & 15) == 0) {
            #pragma unroll
            for (int jj = 0; jj < 32; ++jj) v += Wa[64 + jj] * We[jj * 64 + k];
        }
        Bpack[t] = (short)f2bf(v);
    }
}

// Per-node: z = h@Wn^T (fp32), y16 = bf16(z@W2a^T), asrc = z.Wa[0:64], adst = z.Wa[96:160]
__global__ __launch_bounds__(256) void node_kernel(
    const float* __restrict__ h, const float* __restrict__ Wn,
    const float* __restrict__ W2, const float* __restrict__ Wa,
    float* __restrict__ z, unsigned short* __restrict__ y16,
    float* __restrict__ asrc, float* __restrict__ adst)
{
    __shared__ float sWn[64 * 132];
    __shared__ float sW2a[64 * 68];
    __shared__ float sh[4][128];
    __shared__ float sz[4][64];
    int t = threadIdx.x;
    for (int idx = t; idx < 64 * 128; idx += 256)
        sWn[(idx >> 7) * 132 + (idx & 127)] = Wn[idx];
    for (int idx = t; idx < 64 * 64; idx += 256)
        sW2a[(idx >> 6) * 68 + (idx & 63)] = W2[(idx >> 6) * 96 + (idx & 63)];
    int w = t >> 6, l = t & 63;
    float wa0 = Wa[l], wa2 = Wa[96 + l];
    __syncthreads();
    for (int n0 = blockIdx.x * 4; n0 < N_NODES; n0 += gridDim.x * 4) {
        if (t < 128) {
            int nn = t >> 5, c4 = t & 31;
            int n = n0 + nn;
            if (n < N_NODES)
                ((float4*)&sh[nn][0])[c4] = ((const float4*)h)[(size_t)n * 32 + c4];
        }
        __syncthreads();
        int n = n0 + w;
        if (n < N_NODES) {
            float acc = 0.f;
            #pragma unroll
            for (int qq = 0; qq < 32; ++qq) {
                float4 wv = *(const float4*)&sWn[l * 132 + qq * 4];
                float4 hv = *(const float4*)&sh[w][qq * 4];
                acc += wv.x * hv.x + wv.y * hv.y + wv.z * hv.z + wv.w * hv.w;
            }
            z[(size_t)n * 64 + l] = acc;
            sz[w][l] = acc;
            float p0 = acc * wa0, p1 = acc * wa2;
            #pragma unroll
            for (int off = 32; off; off >>= 1) {
                p0 += __shfl_xor(p0, off);
                p1 += __shfl_xor(p1, off);
            }
            if (l == 0) { asrc[n] = p0; adst[n] = p1; }
        }
        __syncthreads();
        if (n < N_NODES) {
            float acc = 0.f;
            #pragma unroll
            for (int qq = 0; qq < 16; ++qq) {
                float4 wv = *(const float4*)&sW2a[l * 68 + qq * 4];
                float4 zv = *(const float4*)&sz[w][qq * 4];
                acc += wv.x * zv.x + wv.y * zv.y + wv.z * zv.z + wv.w * zv.w;
            }
            y16[(size_t)n * 64 + l] = f2bf(acc);
        }
        __syncthreads();
    }
}

// ---- CSR build ----
__global__ void hist_kernel(const int* __restrict__ dst, int* __restrict__ degi,
                            int* __restrict__ ranks) {
    int e = blockIdx.x * 256 + threadIdx.x;
    if (e < N_EDGES) ranks[e] = atomicAdd(&degi[dst[e]], 1);
}

__global__ __launch_bounds__(256) void scan1_kernel(const int* __restrict__ degi,
                                                    int* __restrict__ partial) {
    int t = threadIdx.x, i = blockIdx.x * 256 + t;
    int d = (i < N_NODES) ? degi[i] : 0;
    #pragma unroll
    for (int off = 32; off; off >>= 1) d += __shfl_down(d, off);
    __shared__ int wsum[4];
    if ((t & 63) == 0) wsum[t >> 6] = d;
    __syncthreads();
    if (t == 0) partial[blockIdx.x] = wsum[0] + wsum[1] + wsum[2] + wsum[3];
}

__global__ __launch_bounds__(256) void scan2_kernel(int* __restrict__ partial) {
    __shared__ int s[256];
    int t = threadIdx.x;
    int v = (t < NB1) ? partial[t] : 0;
    s[t] = v; __syncthreads();
    for (int off = 1; off < 256; off <<= 1) {
        int x = (t >= off) ? s[t - off] : 0;
        __syncthreads();
        s[t] += x;
        __syncthreads();
    }
    if (t < NB1) partial[t] = s[t] - v;   // exclusive, in place
}

__global__ __launch_bounds__(256) void scan3_kernel(const int* __restrict__ degi,
                                                    const int* __restrict__ partial,
                                                    int* __restrict__ start) {
    __shared__ int s[256];
    int t = threadIdx.x, i = blockIdx.x * 256 + t;
    int d = (i < N_NODES) ? degi[i] : 0;
    s[t] = d; __syncthreads();
    for (int off = 1; off < 256; off <<= 1) {
        int x = (t >= off) ? s[t - off] : 0;
        __syncthreads();
        s[t] += x;
        __syncthreads();
    }
    if (i < N_NODES) start[i] = partial[blockIdx.x] + s[t] - d;
}

// 8B scatter into 6.4MB target: L2-absorbed (lines accumulate many slots before evict)
__global__ void scatter_kernel(const int* __restrict__ src, const int* __restrict__ dst,
                               const int* __restrict__ ranks, const int* __restrict__ start,
                               int2* __restrict__ edata) {
    int e = blockIdx.x * 256 + threadIdx.x;
    if (e < N_EDGES) edata[start[dst[e]] + ranks[e]] = make_int2(e, src[e]);
}

// ---- Edge pass: stream edge_feat (edge order), MFMA -> g (cols 0..31) and
//      p = ef.wca via third MFMA pair (col 0). ALL writes coalesced in edge
//      order: gout[e] (64B) + exarr[e] (4B). No scatter, no in-loop shfl. ----
__global__ __launch_bounds__(256, 2) void edge_kernel(
    const float* __restrict__ edge_feat, const int* __restrict__ src,
    const int* __restrict__ dst, const float* __restrict__ asrc,
    const float* __restrict__ adst, const short* __restrict__ Bpack,
    unsigned* __restrict__ gout, float* __restrict__ exarr)
{
    int t = threadIdx.x, w = t >> 6, l = t & 63;
    int c = l & 15, G = l >> 4;
    int wbase = blockIdx.x * 256 + w * 64;   // grid exact: 3125*256 = 800000

    const bf16x8* Bp = (const bf16x8*)Bpack;
    bf16x8 b00 = Bp[0 * 64 + l];   // s=0, cols 0-15
    bf16x8 b01 = Bp[1 * 64 + l];   // s=0, cols 16-31
    bf16x8 b10 = Bp[2 * 64 + l];   // s=1, cols 0-15
    bf16x8 b11 = Bp[3 * 64 + l];   // s=1, cols 16-31
    bf16x8 b2a = Bp[4 * 64 + l];   // s=0, wca col0
    bf16x8 b2b = Bp[5 * 64 + l];   // s=1, wca col0

    // apre for this wave's 64 edges, one per lane; transpose to consumption
    // order via 16 one-time bpermutes (Ra[4k+r] = apre of edge 16k+4G+r)
    int e = wbase + l;
    float apre = asrc[src[e]] + adst[dst[e]];
    float Ra[16];
    #pragma unroll
    for (int k = 0; k < 4; ++k) {
        #pragma unroll
        for (int r = 0; r < 4; ++r)
            Ra[4 * k + r] = __shfl(apre, 16 * k + 4 * G + r);
    }

    // prefetch batch 0: lane holds ef[wbase+c][kk = 32s + 8G + j]
    const float* efr = edge_feat + (size_t)(wbase + c) * 64 + G * 8;
    float4 n0 = *(const float4*)(efr);
    float4 n1 = *(const float4*)(efr + 4);
    float4 n2 = *(const float4*)(efr + 32);
    float4 n3 = *(const float4*)(efr + 36);

    #pragma unroll
    for (int k = 0; k < 4; ++k) {
        float4 c0 = n0, c1 = n1, c2 = n2, c3 = n3;
        if (k < 3) {   // issue next batch's loads before this batch's compute
            const float* efn = edge_feat + (size_t)(wbase + 16 * (k + 1) + c) * 64 + G * 8;
            n0 = *(const float4*)(efn);
            n1 = *(const float4*)(efn + 4);
            n2 = *(const float4*)(efn + 32);
            n3 = *(const float4*)(efn + 36);
        }
        bf16x8 a0, a1;
        a0[0] = (short)f2bf(c0.x); a0[1] = (short)f2bf(c0.y);
        a0[2] = (short)f2bf(c0.z); a0[3] = (short)f2bf(c0.w);
        a0[4] = (short)f2bf(c1.x); a0[5] = (short)f2bf(c1.y);
        a0[6] = (short)f2bf(c1.z); a0[7] = (short)f2bf(c1.w);
        a1[0] = (short)f2bf(c2.x); a1[1] = (short)f2bf(c2.y);
        a1[2] = (short)f2bf(c2.z); a1[3] = (short)f2bf(c2.w);
        a1[4] = (short)f2bf(c3.x); a1[5] = (short)f2bf(c3.y);
        a1[6] = (short)f2bf(c3.z); a1[7] = (short)f2bf(c3.w);

        f32x4 acc0 = {0.f, 0.f, 0.f, 0.f};
        f32x4 acc1 = {0.f, 0.f, 0.f, 0.f};
        f32x4 acc2 = {0.f, 0.f, 0.f, 0.f};
        acc0 = __builtin_amdgcn_mfma_f32_16x16x32_bf16(a0, b00, acc0, 0, 0, 0);
        acc0 = __builtin_amdgcn_mfma_f32_16x16x32_bf16(a1, b10, acc0, 0, 0, 0);
        acc1 = __builtin_amdgcn_mfma_f32_16x16x32_bf16(a0, b01, acc1, 0, 0, 0);
        acc1 = __builtin_amdgcn_mfma_f32_16x16x32_bf16(a1, b11, acc1, 0, 0, 0);
        acc2 = __builtin_amdgcn_mfma_f32_16x16x32_bf16(a0, b2a, acc2, 0, 0, 0);
        acc2 = __builtin_amdgcn_mfma_f32_16x16x32_bf16(a1, b2b, acc2, 0, 0, 0);
        // acc0[r]=g[e=wbase+16k+4G+r][j=c], acc1[r]=g[..][16+c], acc2[r]=p (c==0)

        #pragma unroll
        for (int r = 0; r < 4; ++r) {
            int eo = wbase + 16 * k + 4 * G + r;
            gout[(size_t)eo * 16 + c] = pack2bf(acc0[r], acc1[r]);
            if (c == 0) {
                float a = Ra[4 * k + r] + acc2[r];
                float sg = a > 0.f ? a : 0.01f * a;
                exarr[eo] = __expf(sg);   // segmax shift mathematically redundant
            }
        }
    }
}

// ---- Pass B: per-node walk; edata streamed, g gathered (L3-resident 51MB),
//      ex + y16 gathered (L2-resident) ----
__global__ __launch_bounds__(256) void agg_kernel(
    const unsigned* __restrict__ gout, const float* __restrict__ exarr,
    const int2* __restrict__ edata, const ushort4* __restrict__ y16v,
    const int* __restrict__ start, const int* __restrict__ degi,
    const float* __restrict__ z, const float* __restrict__ W2,
    float* __restrict__ out)
{
    __shared__ float stu[4][164];    // [64:128)=uy, [128:160)=v32
    __shared__ float sW2b[64 * 36];
    int t = threadIdx.x, w = t >> 6, l = t & 63, g = l >> 4, q = l & 15;
    for (int idx = t; idx < 64 * 32; idx += 256)
        sW2b[(idx >> 5) * 36 + (idx & 31)] = W2[(idx >> 5) * 96 + 64 + (idx & 31)];
    __syncthreads();

    int d    = blockIdx.x * 4 + w;           // grid exact: 12500*4 = 50000
    int base = __builtin_amdgcn_readfirstlane(start[d]);
    int deg  = __builtin_amdgcn_readfirstlane(degi[d]);
    float2 tg = make_float2(0.f, 0.f);
    float4 uy4 = make_float4(0.f, 0.f, 0.f, 0.f);
    float den = 0.f;

    for (int c = 0; c < deg; c += 8) {
        int i0 = c + g, i1 = c + 4 + g;
        bool v0 = i0 < deg, v1 = i1 < deg;
        int2 m0 = edata[base + (v0 ? i0 : 0)];
        int2 m1 = edata[base + (v1 ? i1 : 0)];
        unsigned ga = gout[(size_t)m0.x * 16 + q];
        unsigned gb = gout[(size_t)m1.x * 16 + q];
        ushort4 ya = y16v[(size_t)m0.y * 16 + q];
        ushort4 yb = y16v[(size_t)m1.y * 16 + q];
        float ex0 = v0 ? exarr[m0.x] : 0.f;
        float ex1 = v1 ? exarr[m1.x] : 0.f;

        tg.x += ex0 * bf2f((unsigned short)(ga & 0xffffu));
        tg.y += ex0 * bf2f((unsigned short)(ga >> 16));
        uy4.x += ex0 * bf2f(ya.x); uy4.y += ex0 * bf2f(ya.y);
        uy4.z += ex0 * bf2f(ya.z); uy4.w += ex0 * bf2f(ya.w);
        den += ex0;

        tg.x += ex1 * bf2f((unsigned short)(gb & 0xffffu));
        tg.y += ex1 * bf2f((unsigned short)(gb >> 16));
        uy4.x += ex1 * bf2f(yb.x); uy4.y += ex1 * bf2f(yb.y);
        uy4.z += ex1 * bf2f(yb.z); uy4.w += ex1 * bf2f(yb.w);
        den += ex1;
    }

    // combine the 4 edge-slot groups
    tg.x += __shfl_xor(tg.x, 16); tg.x += __shfl_xor(tg.x, 32);
    tg.y += __shfl_xor(tg.y, 16); tg.y += __shfl_xor(tg.y, 32);
    uy4.x += __shfl_xor(uy4.x, 16); uy4.x += __shfl_xor(uy4.x, 32);
    uy4.y += __shfl_xor(uy4.y, 16); uy4.y += __shfl_xor(uy4.y, 32);
    uy4.z += __shfl_xor(uy4.z, 16); uy4.z += __shfl_xor(uy4.z, 32);
    uy4.w += __shfl_xor(uy4.w, 16); uy4.w += __shfl_xor(uy4.w, 32);
    den += __shfl_xor(den, 16); den += __shfl_xor(den, 32);

    if (l < 16) {
        *(float4*)&stu[w][64 + q * 4] = uy4;
        stu[w][128 + q] = tg.x;        // v32[j=q]
        stu[w][144 + q] = tg.y;        // v32[j=16+q]
    }
    // same wave writes+reads stu[w] -> in-order, no barrier needed

    if (deg > 0) {
        float r = 0.f;
        #pragma unroll
        for (int k = 0; k < 8; ++k) {
            float4 wv = *(const float4*)&sW2b[l * 36 + k * 4];
            float4 vv = *(const float4*)&stu[w][128 + k * 4];
            r += wv.x * vv.x + wv.y * vv.y + wv.z * vv.z + wv.w * vv.w;
        }
        out[(size_t)d * 64 + l] = (r + stu[w][64 + l]) / den;
    } else {
        out[(size_t)d * 64 + l] = z[(size_t)d * 64 + l];
    }
}

extern "C" void kernel_launch(void* const* d_in, const int* in_sizes, int n_in,
                              void* d_out, int out_size, void* d_ws, size_t ws_size,
                              hipStream_t stream) {
    const float* h         = (const float*)d_in[0];
    const float* edge_feat = (const float*)d_in[1];
    const int*   src       = (const int*)d_in[2];
    const int*   dst       = (const int*)d_in[3];
    const float* Wn        = (const float*)d_in[4];
    const float* We        = (const float*)d_in[5];
    const float* Wa        = (const float*)d_in[6];
    const float* W2        = (const float*)d_in[7];
    float* out = (float*)d_out;

    char* p = (char*)d_ws;
    float*          z      = (float*)p;          p += (size_t)N_NODES * 64 * 4;   // 12.8 MB
    unsigned short* y16    = (unsigned short*)p; p += (size_t)N_NODES * 64 * 2;   // 6.4 MB
    float*          asrc   = (float*)p;          p += (size_t)N_NODES * 4;
    float*          adst   = (float*)p;          p += (size_t)N_NODES * 4;
    int*            degi   = (int*)p;            p += (size_t)N_NODES * 4;
    int*            start  = (int*)p;            p += (size_t)N_NODES * 4;
    int*            ranks  = (int*)p;            p += (size_t)N_EDGES * 4;        // 3.2 MB
    int*            partial= (int*)p;            p += (size_t)256 * 4;
    short*          Bpack  = (short*)p;          p += (size_t)3072 * 2;           // 6 KB
    int2*           edata  = (int2*)p;           p += (size_t)N_EDGES * 8;        // 6.4 MB
    unsigned*       gout   = (unsigned*)p;       p += (size_t)N_EDGES * 16 * 4;   // 51.2 MB
    float*          exarr  = (float*)p;          p += (size_t)N_EDGES * 4;        // 3.2 MB

    kw_kernel<<<NB1, 256, 0, stream>>>(We, Wa, Bpack, degi);
    node_kernel<<<1024, 256, 0, stream>>>(h, Wn, W2, Wa, z, y16, asrc, adst);
    hist_kernel<<<(N_EDGES + 255) / 256, 256, 0, stream>>>(dst, degi, ranks);
    scan1_kernel<<<NB1, 256, 0, stream>>>(degi, partial);
    scan2_kernel<<<1, 256, 0, stream>>>(partial);
    scan3_kernel<<<NB1, 256, 0, stream>>>(degi, partial, start);
    scatter_kernel<<<(N_EDGES + 255) / 256, 256, 0, stream>>>(src, dst, ranks, start, edata);
    edge_kernel<<<N_EDGES / 256, 256, 0, stream>>>(edge_feat, src, dst, asrc, adst,
                                                   Bpack, gout, exarr);
    agg_kernel<<<N_NODES / 4, 256, 0, stream>>>(gout, exarr, edata, (const ushort4*)y16,
                                                start, degi, z, W2, out);
}